// Round 15
// baseline (162.106 us; speedup 1.0000x reference)
//
#include <hip/hip_runtime.h>
#include <math.h>

#define BB 8
#define CCH 32
#define HH 128
#define WW 128
#define OUTC 32
#define NPIX (BB*HH*WW)          // 131072
#define HWP 131                   // padded-coord clamp limit
#define NCONVBLK 2048             // conv blocks (64 px each)

// workspace layout (float offsets) — ~10.6 MB
#define WS_XBF   0                                   // bf16 x_t [b][i][j][c], 8 MB (2097152 f)
#define WS_CONV4 2097152                             // pre-BN conv, 4 f/px, 2 MB
#define WS_PART  (WS_CONV4 + BB*HH*WW*4)             // 2048*8 f per-block stats partials
#define WS_BNAB  (WS_PART + NCONVBLK*8)              // 8 f
#define WS_WKB   (WS_BNAB + 8)                       // 16384 ushort bf16 W[o][k], k=n*32+c

// k_main LDS tile: rows i0-4..i0+7 (12), cols j0-4..j0+35 (40), 5-group padding
// offset(r,cc,q) = ((r*40+cc)*5 + q)*8 ushorts; (r,cc) stride 80B
#define TILE_USH (12*40*5*8)                         // 19200 ushorts = 38400 B

typedef __attribute__((ext_vector_type(8))) short short8;
typedef __attribute__((ext_vector_type(4))) float f32x4;

__device__ __forceinline__ unsigned short f2bf(float f) {
    unsigned u = __float_as_uint(f);
    unsigned r = (u + 0x7FFFu + ((u >> 16) & 1u)) >> 16;   // RTNE
    return (unsigned short)r;
}
__device__ __forceinline__ unsigned pk2(float a, float b) {
    return (unsigned)f2bf(a) | ((unsigned)f2bf(b) << 16);
}
__device__ __forceinline__ float bflo(unsigned w) { return __uint_as_float(w << 16); }
__device__ __forceinline__ float bfhi(unsigned w) { return __uint_as_float(w & 0xFFFF0000u); }

// ---------------- K1: fused transpose(bf16) | NCHW conv+partials | wkb ------
__global__ __launch_bounds__(256) void k_fused1(const float* __restrict__ x,
        const float* __restrict__ w_vrt, const float* __restrict__ b_vrt,
        const float* __restrict__ w_hrz, const float* __restrict__ b_hrz,
        const float* __restrict__ w_pk, float* __restrict__ ws) {
    __shared__ float tile[32][33];
    __shared__ float red[4][64][4];
    int blk = blockIdx.x, t = threadIdx.x;
    if (blk < 4096) {
        // ---- transpose x (B,C,H,W) -> x_bf bf16 [b][i][j][c] (8 MB)
        int j0 = (blk & 3) << 5;
        int bi = blk >> 2;               // b*H + i
        int b = bi >> 7, i = bi & 127;
        int tx = t & 31, ty = t >> 5;
        #pragma unroll
        for (int c = ty; c < 32; c += 8)
            tile[c][tx] = x[(((size_t)b*CCH + c)*HH + i)*WW + j0 + tx];
        __syncthreads();
        unsigned short* xbf = (unsigned short*)(ws + WS_XBF);
        #pragma unroll
        for (int jj = ty; jj < 32; jj += 8)
            xbf[(((size_t)bi)*WW + j0 + jj)*CCH + tx] = f2bf(tile[tx][jj]);
    } else if (blk < 4096 + NCONVBLK) {
        // ---- conv: 64 px of row (b,i), from ORIGINAL fp32 NCHW x (gates fp32!)
        int cb = blk - 4096;
        int idx0 = cb * 64;
        int b = idx0 >> 14, ij0 = idx0 & 16383, i = ij0 >> 7, j0c = ij0 & 127;
        int px = t & 63;
        int grp = __builtin_amdgcn_readfirstlane(t >> 6);  // wave-uniform ch group
        float v0 = 0.f, v1 = 0.f, h0 = 0.f, h1 = 0.f;
        for (int c8 = 0; c8 < 8; c8++) {
            int c = grp * 8 + c8;
            const float* basec = x + ((size_t)(b*CCH + c))*HH*WW;
            #pragma unroll
            for (int k = 0; k < 7; k++) {
                float wv0 = w_vrt[c*7 + k], wv1 = w_vrt[224 + c*7 + k];
                int gr = i + k - 3;
                if (gr >= 0 && gr < HH) {
                    float xv = basec[(size_t)gr*WW + j0c + px];
                    v0 += wv0 * xv; v1 += wv1 * xv;
                }
                float wh0 = w_hrz[c*7 + k], wh1 = w_hrz[224 + c*7 + k];
                int gc = j0c + px + k - 3;
                if (gc >= 0 && gc < WW) {
                    float xh = basec[(size_t)i*WW + gc];
                    h0 += wh0 * xh; h1 += wh1 * xh;
                }
            }
        }
        red[grp][px][0] = v0; red[grp][px][1] = v1;
        red[grp][px][2] = h0; red[grp][px][3] = h1;
        __syncthreads();
        if (grp == 0) {
            float fv0 = red[0][px][0]+red[1][px][0]+red[2][px][0]+red[3][px][0] + b_vrt[0];
            float fv1 = red[0][px][1]+red[1][px][1]+red[2][px][1]+red[3][px][1] + b_vrt[1];
            float fh0 = red[0][px][2]+red[1][px][2]+red[2][px][2]+red[3][px][2] + b_hrz[0];
            float fh1 = red[0][px][3]+red[1][px][3]+red[2][px][3]+red[3][px][3] + b_hrz[1];
            float4* conv4 = (float4*)(ws + WS_CONV4);
            conv4[idx0 + px] = make_float4(fv0, fv1, fh0, fh1);
            float stv[8] = {fv0, fv1, fh0, fh1, fv0*fv0, fv1*fv1, fh0*fh0, fh1*fh1};
            #pragma unroll
            for (int u = 0; u < 8; u++) {
                float s = stv[u];
                for (int off = 32; off; off >>= 1) s += __shfl_down(s, off);
                if (px == 0) ws[WS_PART + cb*8 + u] = s;   // deterministic, no atomics
            }
        }
    } else {
        // ---- wkb: bf16 W[o][k], k = n*32+c
        unsigned short* wkb = (unsigned short*)(ws + WS_WKB);
        int e = (blk - 4096 - NCONVBLK) * 2048 + t;
        for (int u = 0; u < 8; u++, e += 256) {
            int o = e >> 9, n = (e >> 5) & 15, c = e & 31;
            wkb[o*512 + n*32 + c] = f2bf(w_pk[((o*32 + c) << 4) + n]);
        }
    }
}

// ---------------- K2: reduce partials -> BN affine consts -------------------
__global__ __launch_bounds__(256) void k_prep(
        const float* __restrict__ g_vrt, const float* __restrict__ be_vrt,
        const float* __restrict__ g_hrz, const float* __restrict__ be_hrz,
        float* __restrict__ ws) {
    __shared__ float acc[32][8];
    int t = threadIdx.x;
    int s = t & 7, chunk = t >> 3;          // 32 chunks of 64 blocks
    float sum = 0.f;
    for (int m = 0; m < 64; m++)
        sum += ws[WS_PART + (size_t)(chunk*64 + m)*8 + s];
    acc[chunk][s] = sum;
    __syncthreads();
    if (t < 8) {
        float tot = 0.f;
        #pragma unroll
        for (int c = 0; c < 32; c++) tot += acc[c][t];
        acc[0][t] = tot;
    }
    __syncthreads();
    if (t < 4) {
        const float cnt = (float)NPIX;
        float mean = acc[0][t] / cnt;
        float var  = acc[0][4 + t] / cnt - mean * mean;
        float gamma = (t < 2) ? g_vrt[t] : g_hrz[t - 2];
        float beta  = (t < 2) ? be_vrt[t] : be_hrz[t - 2];
        float a = gamma * rsqrtf(var + 1e-5f);
        ws[WS_BNAB + t]     = a;
        ws[WS_BNAB + 4 + t] = beta - mean * a;
    }
}

// per-(pixel,n) sampling: returns bf16 B-fragment (8 ch = quad slice)
__device__ __forceinline__ short8 sample_frag(const unsigned short* tile,
        const float* xc8, const float* gbv, float fi, float fj, int n,
        float prx, float pry, int i0, int j0, int quad) {
    float mx = 0.f, my = 0.f;
    if (n < 4)       mx = -gbv[0];
    else if (n < 8)  my =  gbv[3];
    else if (n < 12) mx =  gbv[1];
    else             my = -gbv[2];
    float px = fi + prx + mx;
    float py = fj + pry + my;
    float qlx = floorf(px), qly = floorf(py);
    int qlxi = min(max((int)qlx, 0), HWP);
    int qlyi = min(max((int)qly, 0), HWP);
    int qrxi = min(max((int)qlx + 1, 0), HWP);
    int qryi = min(max((int)qly + 1, 0), HWP);
    float pxc = fminf(fmaxf(px, 0.f), (float)HWP);
    float pyc = fminf(fmaxf(py, 0.f), (float)HWP);
    float glt = (1.f + ((float)qlxi - pxc)) * (1.f + ((float)qlyi - pyc));
    float grb = (1.f - ((float)qrxi - pxc)) * (1.f - ((float)qryi - pyc));
    // edge pad: x_pad[a] = x[clamp(a-2,0,127)]
    int ltr = min(max(qlxi - 2, 0), HH - 1), ltc = min(max(qlyi - 2, 0), WW - 1);
    int rbr = min(max(qrxi - 2, 0), HH - 1), rbc = min(max(qryi - 2, 0), WW - 1);
    int lt_off = (((ltr - i0 + 4)*40 + (ltc - j0 + 4))*5 + quad) * 8;
    int rb_off = (((rbr - i0 + 4)*40 + (rbc - j0 + 4))*5 + quad) * 8;
    uint4 lw = *(const uint4*)(tile + lt_off);
    uint4 rw = *(const uint4*)(tile + rb_off);
    float d0 = xc8[0] - (glt*bflo(lw.x) + grb*bflo(rw.x));
    float d1 = xc8[1] - (glt*bfhi(lw.x) + grb*bfhi(rw.x));
    float d2 = xc8[2] - (glt*bflo(lw.y) + grb*bflo(rw.y));
    float d3 = xc8[3] - (glt*bfhi(lw.y) + grb*bfhi(rw.y));
    float d4 = xc8[4] - (glt*bflo(lw.z) + grb*bflo(rw.z));
    float d5 = xc8[5] - (glt*bfhi(lw.z) + grb*bfhi(rw.z));
    float d6 = xc8[6] - (glt*bflo(lw.w) + grb*bflo(rw.w));
    float d7 = xc8[7] - (glt*bfhi(lw.w) + grb*bfhi(rw.w));
    uint4 bw;
    bw.x = pk2(d0, d1); bw.y = pk2(d2, d3);
    bw.z = pk2(d4, d5); bw.w = pk2(d6, d7);
    return *(short8*)&bw;
}

// ---------------- K3: MFMA, 2 pixel-tiles per wave, bf16 direct staging -----
// 1024 blocks x 256 thr. Block = (b, rows i0..i0+3, cols j0..j0+31) = 128 px.
// Wave w (0..3): row ir = i0+w; tile A = cols j0+pl, tile B = cols j0+16+pl.
// Staging: direct bf16 uint4 copy (no conversion). Centers read from LDS tile.
__global__ __launch_bounds__(256, 4) void k_main(const float* __restrict__ ws,
        const float* __restrict__ b_pk, float* __restrict__ out) {
    __shared__ unsigned short tile[TILE_USH];     // 38400 B
    const unsigned short* xbf = (const unsigned short*)(ws + WS_XBF);
    const float* bnab = ws + WS_BNAB;
    const unsigned short* wkb = (const unsigned short*)(ws + WS_WKB);
    const float prfx[16] = {-2,-2,-2,-2, -2,-1, 0, 1,  2, 2, 2, 2, -1, 0, 1, 2};
    const float prfy[16] = {-2,-1, 0, 1,  2, 2, 2, 2, -1, 0, 1, 2, -2,-2,-2,-2};

    int t = threadIdx.x;
    int blk = blockIdx.x;                 // b(3b) | ig(5b) | jh(2b)
    int b = blk >> 7;
    int i0 = ((blk >> 2) & 31) * 4;
    int j0 = (blk & 3) * 32;

    // ---- staging: bf16 uint4 direct copy (edge clamp), 12 rows x 40 cols
    for (int s = t; s < 12*40*4; s += 256) {
        int q = s & 3, cc = (s >> 2) % 40, r = (s >> 2) / 40;
        int gr = min(max(i0 - 4 + r, 0), HH - 1);
        int gc = min(max(j0 - 4 + cc, 0), WW - 1);
        uint4 v = *(const uint4*)(xbf + (((size_t)(b*HH + gr))*WW + gc)*CCH + q*8);
        *(uint4*)(tile + ((r*40 + cc)*5 + q)*8) = v;
    }
    __syncthreads();

    int w = t >> 6, pl = t & 15, quad = (t >> 4) & 3;
    int ir = i0 + w;
    int pjA = j0 + pl, pjB = j0 + 16 + pl;
    int pixA = (b << 14) + ir * WW + pjA;
    int pixB = pixA + 16;

    // centers from the LDS tile (bf16 -> fp32)
    float xcA[8], xcB[8];
    {
        int rr = ir - i0 + 4;
        uint4 cwA = *(const uint4*)(tile + ((rr*40 + (pjA - j0 + 4))*5 + quad)*8);
        uint4 cwB = *(const uint4*)(tile + ((rr*40 + (pjB - j0 + 4))*5 + quad)*8);
        xcA[0]=bflo(cwA.x); xcA[1]=bfhi(cwA.x); xcA[2]=bflo(cwA.y); xcA[3]=bfhi(cwA.y);
        xcA[4]=bflo(cwA.z); xcA[5]=bfhi(cwA.z); xcA[6]=bflo(cwA.w); xcA[7]=bfhi(cwA.w);
        xcB[0]=bflo(cwB.x); xcB[1]=bfhi(cwB.x); xcB[2]=bflo(cwB.y); xcB[3]=bfhi(cwB.y);
        xcB[4]=bflo(cwB.z); xcB[5]=bfhi(cwB.z); xcB[6]=bflo(cwB.w); xcB[7]=bfhi(cwB.w);
    }
    // gates for both pixels (fp32 path — untouched)
    const float4* conv4 = (const float4*)(ws + WS_CONV4);
    float4 cvA = conv4[pixA], cvB = conv4[pixB];
    float gbvA[4], gbvB[4];
    gbvA[0] = 2.f / (1.f + expf(-(cvA.x * bnab[0] + bnab[4])));
    gbvA[1] = 2.f / (1.f + expf(-(cvA.y * bnab[1] + bnab[5])));
    gbvA[2] = 2.f / (1.f + expf(-(cvA.z * bnab[2] + bnab[6])));
    gbvA[3] = 2.f / (1.f + expf(-(cvA.w * bnab[3] + bnab[7])));
    gbvB[0] = 2.f / (1.f + expf(-(cvB.x * bnab[0] + bnab[4])));
    gbvB[1] = 2.f / (1.f + expf(-(cvB.y * bnab[1] + bnab[5])));
    gbvB[2] = 2.f / (1.f + expf(-(cvB.z * bnab[2] + bnab[6])));
    gbvB[3] = 2.f / (1.f + expf(-(cvB.w * bnab[3] + bnab[7])));

    f32x4 accA0 = {0.f,0.f,0.f,0.f}, accA1 = {0.f,0.f,0.f,0.f};
    f32x4 accB0 = {0.f,0.f,0.f,0.f}, accB1 = {0.f,0.f,0.f,0.f};
    float fi = (float)ir + 2.f;
    float fjA = (float)pjA + 2.f, fjB = (float)pjB + 2.f;

    // weight prefetch pipeline (A-frags shared by both pixel tiles)
    short8 a0 = *(const short8*)(wkb + (size_t)pl * 512 + quad*8);
    short8 a1 = *(const short8*)(wkb + (size_t)(pl + 16) * 512 + quad*8);

    #pragma unroll
    for (int n = 0; n < 16; n++) {
        short8 na0 = a0, na1 = a1;
        if (n < 15) {
            na0 = *(const short8*)(wkb + (size_t)pl * 512 + (n+1)*32 + quad*8);
            na1 = *(const short8*)(wkb + (size_t)(pl + 16) * 512 + (n+1)*32 + quad*8);
        }
        short8 bfA = sample_frag(tile, xcA, gbvA, fi, fjA, n, prfx[n], prfy[n], i0, j0, quad);
        short8 bfB = sample_frag(tile, xcB, gbvB, fi, fjB, n, prfx[n], prfy[n], i0, j0, quad);
        accA0 = __builtin_amdgcn_mfma_f32_16x16x32_bf16(a0, bfA, accA0, 0, 0, 0);
        accA1 = __builtin_amdgcn_mfma_f32_16x16x32_bf16(a1, bfA, accA1, 0, 0, 0);
        accB0 = __builtin_amdgcn_mfma_f32_16x16x32_bf16(a0, bfB, accB0, 0, 0, 0);
        accB1 = __builtin_amdgcn_mfma_f32_16x16x32_bf16(a1, bfB, accB1, 0, 0, 0);
        a0 = na0; a1 = na1;
    }
    // epilogue: col = pl (pixel), row = quad*4+reg (out channel)
    float* opA = out + (size_t)b * (OUTC*HH*WW) + ir * WW + pjA;
    float* opB = opA + 16;
    #pragma unroll
    for (int r = 0; r < 4; r++) {
        int o = quad*4 + r;
        float bo = b_pk[o], bo16 = b_pk[o + 16];
        opA[(size_t)o * (HH*WW)]        = accA0[r] + bo;
        opA[(size_t)(o + 16) * (HH*WW)] = accA1[r] + bo16;
        opB[(size_t)o * (HH*WW)]        = accB0[r] + bo;
        opB[(size_t)(o + 16) * (HH*WW)] = accB1[r] + bo16;
    }
}

extern "C" void kernel_launch(void* const* d_in, const int* in_sizes, int n_in,
                              void* d_out, int out_size, void* d_ws, size_t ws_size,
                              hipStream_t stream) {
    const float* x      = (const float*)d_in[0];
    const float* w_vrt  = (const float*)d_in[1];
    const float* b_vrt  = (const float*)d_in[2];
    const float* g_vrt  = (const float*)d_in[3];
    const float* be_vrt = (const float*)d_in[4];
    const float* w_hrz  = (const float*)d_in[5];
    const float* b_hrz  = (const float*)d_in[6];
    const float* g_hrz  = (const float*)d_in[7];
    const float* be_hrz = (const float*)d_in[8];
    const float* w_pk   = (const float*)d_in[9];
    const float* b_pk   = (const float*)d_in[10];
    float* ws  = (float*)d_ws;
    float* out = (float*)d_out;

    k_fused1<<<4096 + NCONVBLK + 8, 256, 0, stream>>>(x, w_vrt, b_vrt, w_hrz, b_hrz, w_pk, ws);
    k_prep<<<1, 256, 0, stream>>>(g_vrt, be_vrt, g_hrz, be_hrz, ws);
    k_main<<<1024, 256, 0, stream>>>(ws, b_pk, out);
}